// Round 13
// baseline (318.559 us; speedup 1.0000x reference)
//
#include <hip/hip_runtime.h>
#include <math.h>

#define VOCAB   32000
#define BLTOT   128    // B*L
#define HTOT    64     // H = 8 heads * 8 hph
#define BLT     4      // bl rows accumulated per thread
#define VPB     256    // threads per block (4 waves)
#define VT      4      // vocab rows per thread
#define SLICE   (VPB * VT)                           // 1024 vocab rows per block
#define NSLICE  ((VOCAB + SLICE - 1) / SLICE)        // 32 (tail-guarded)

#define PREP1_BLOCKS 32                              // 8192 threads for f-side
#define PREP2_BLOCKS ((VOCAB * 2 + 255) / 256)       // 250 blocks for EV table

#define LOG2E   1.44269504088896340736f

typedef __fp16 h2 __attribute__((ext_vector_type(2)));

// ---------------------------------------------------------------------------
// Fused prep (single launch, block-range partitioned):
//  blocks [0, 32):    f-side f16 tables in ws (block-uniform in main -> s_load)
//    arrA [bl][jj][8]: {ef0..3, emf0..3} at ws+0      (32 KB)
//    arrC [bl][jj][4]: {cw0..3}          at ws+32768  (16 KB)
//  blocks [32, 282):  v-side exp table EV[jj][v] = {e^v0..3, e^-v0..3} f16,
//    8 MB at ws+49152. Thread = (v, half): reads its own 128 B contiguous
//    vp chunk, writes lane-consecutive in v (coalesced).
//  exp(-|f-v|) = min(ef*e^-v, emf*e^v); one-sided f16 overflow healed by min.
// ---------------------------------------------------------------------------
__global__ void prep_fused(const float* __restrict__ freqs,
                           const float* __restrict__ amps,
                           const float* __restrict__ phases,
                           const float* __restrict__ ip,
                           const float* __restrict__ W,
                           const float4* __restrict__ vp4,
                           void* __restrict__ ws) {
    if (blockIdx.x < PREP1_BLOCKS) {
        int t = blockIdx.x * blockDim.x + threadIdx.x;   // 0 .. 8191
        int bl = t >> 6;
        int j  = t & 63;
        float fe = freqs[t] * LOG2E;
        float cw = amps[t] * cosf(phases[t] - ip[j]) * W[j >> 3];
        int jj = j >> 2, u = j & 3;
        __fp16* pA = (__fp16*)ws;
        __fp16* pC = (__fp16*)((char*)ws + 32768);
        int ia = (bl * 16 + jj) * 8;
        pA[ia + u]     = (__fp16)__builtin_amdgcn_exp2f(fe);    // e^f
        pA[ia + 4 + u] = (__fp16)__builtin_amdgcn_exp2f(-fe);   // e^-f
        pC[(bl * 16 + jj) * 4 + u] = (__fp16)cw;
    } else {
        int t = (blockIdx.x - PREP1_BLOCKS) * blockDim.x + threadIdx.x;  // 0 .. 63999
        if (t >= VOCAB * 2) return;
        int v   = t >> 1;
        int jj0 = (t & 1) * 8;
        float4* evt4 = (float4*)((char*)ws + 49152);
#pragma unroll
        for (int l = 0; l < 8; ++l) {
            int jj = jj0 + l;
            const float4 vf = vp4[v * 16 + jj];
            float ax = vf.x * LOG2E, ay = vf.y * LOG2E;
            float az = vf.z * LOG2E, aw = vf.w * LOG2E;
            h2 ev01  = __builtin_amdgcn_cvt_pkrtz(__builtin_amdgcn_exp2f( ax),
                                                  __builtin_amdgcn_exp2f( ay));
            h2 ev23  = __builtin_amdgcn_cvt_pkrtz(__builtin_amdgcn_exp2f( az),
                                                  __builtin_amdgcn_exp2f( aw));
            h2 emv01 = __builtin_amdgcn_cvt_pkrtz(__builtin_amdgcn_exp2f(-ax),
                                                  __builtin_amdgcn_exp2f(-ay));
            h2 emv23 = __builtin_amdgcn_cvt_pkrtz(__builtin_amdgcn_exp2f(-az),
                                                  __builtin_amdgcn_exp2f(-aw));
            float4 o;
            o.x = __builtin_bit_cast(float, ev01);
            o.y = __builtin_bit_cast(float, ev23);
            o.z = __builtin_bit_cast(float, emv01);
            o.w = __builtin_bit_cast(float, emv23);
            evt4[jj * VOCAB + v] = o;                    // lane-consecutive in v
        }
    }
}

// ---------------------------------------------------------------------------
// Main: grid (x = 32 bl-groups, y = 32 vocab slices); consecutive ids share
// a vocab slice (XCD round-robin keeps it L2-resident). Thread owns VT=4
// vocab rows x BLT=4 bl rows. f-side table via block-uniform pointers ->
// s_load on the scalar pipe (no LDS, no barrier). R13 deltas: (1) fully-OOB
// threads (last slice) exit immediately; (2) jj loop fully unrolled with
// EV loads software-pipelined one jj ahead to hide L2 latency under the
// 8-instr/4-elem inner work.
// ---------------------------------------------------------------------------
__global__ __launch_bounds__(VPB, 8) void
wave_main(const float4* __restrict__ evt4,  // EV table [16][VOCAB]
          const void* __restrict__ uni,     // ws f16 f-side tables
          const float* __restrict__ bptr,   // bias (1 elem)
          float* __restrict__ out) {        // (B*L, VOCAB)
    const int tid = threadIdx.x;
    const int bl0 = blockIdx.x * BLT;                 // 128 = 32*4 exact
    const int v0  = blockIdx.y * SLICE + tid;

    if (v0 >= VOCAB) return;   // all k's OOB (no barriers below) -- tail slice

    const float4* gA = (const float4*)((const char*)uni + (size_t)bl0 * 256);
    const float2* gC = (const float2*)((const char*)uni + 32768 + (size_t)bl0 * 128);

    int vidx[VT];
#pragma unroll
    for (int k = 0; k < VT; ++k) {
        int v = v0 + k * VPB;
        vidx[k] = v < VOCAB ? v : VOCAB - 1;   // clamp loads; stores guarded
    }

    float acc[BLT][VT];
#pragma unroll
    for (int i = 0; i < BLT; ++i)
#pragma unroll
        for (int k = 0; k < VT; ++k) acc[i][k] = 0.0f;

    // software pipeline: EV loads issued one jj ahead
    float4 Ecur[VT], Enxt[VT];
#pragma unroll
    for (int k = 0; k < VT; ++k) Ecur[k] = evt4[0 * VOCAB + vidx[k]];

#pragma unroll
    for (int jj = 0; jj < 16; ++jj) {
        if (jj < 15) {
#pragma unroll
            for (int k = 0; k < VT; ++k)
                Enxt[k] = evt4[(jj + 1) * VOCAB + vidx[k]];   // prefetch
        }
        h2 evA[VT], evB[VT], emvA[VT], emvB[VT];
#pragma unroll
        for (int k = 0; k < VT; ++k) {
            evA[k]  = __builtin_bit_cast(h2, Ecur[k].x);
            evB[k]  = __builtin_bit_cast(h2, Ecur[k].y);
            emvA[k] = __builtin_bit_cast(h2, Ecur[k].z);
            emvB[k] = __builtin_bit_cast(h2, Ecur[k].w);
        }
#pragma unroll
        for (int i = 0; i < BLT; ++i) {
            const float4 A = gA[i * 16 + jj];         // s_load_dwordx4
            const float2 C = gC[i * 16 + jj];         // s_load_dwordx2
            const h2 ef01 = __builtin_bit_cast(h2, A.x);
            const h2 ef23 = __builtin_bit_cast(h2, A.y);
            const h2 em01 = __builtin_bit_cast(h2, A.z);
            const h2 em23 = __builtin_bit_cast(h2, A.w);
            const h2 cw01 = __builtin_bit_cast(h2, C.x);
            const h2 cw23 = __builtin_bit_cast(h2, C.y);
#pragma unroll
            for (int k = 0; k < VT; ++k) {
                h2 m01 = __builtin_elementwise_min(ef01 * emvA[k], em01 * evA[k]);
                h2 m23 = __builtin_elementwise_min(ef23 * emvB[k], em23 * evB[k]);
                acc[i][k] = __builtin_amdgcn_fdot2(m01, cw01, acc[i][k], false);
                acc[i][k] = __builtin_amdgcn_fdot2(m23, cw23, acc[i][k], false);
            }
        }
#pragma unroll
        for (int k = 0; k < VT; ++k) Ecur[k] = Enxt[k];
    }

    const float b0 = bptr[0];
#pragma unroll
    for (int i = 0; i < BLT; ++i)
#pragma unroll
        for (int k = 0; k < VT; ++k) {
            int v = v0 + k * VPB;
            if (v < VOCAB)
                out[(bl0 + i) * VOCAB + v] = acc[i][k] + b0;   // coalesced per k
        }
}

extern "C" void kernel_launch(void* const* d_in, const int* in_sizes, int n_in,
                              void* d_out, int out_size, void* d_ws, size_t ws_size,
                              hipStream_t stream) {
    const float* freqs  = (const float*)d_in[0];
    const float* amps   = (const float*)d_in[1];
    const float* phases = (const float*)d_in[2];
    const float* vp     = (const float*)d_in[3];
    const float* ip     = (const float*)d_in[4];
    const float* W      = (const float*)d_in[5];
    const float* b      = (const float*)d_in[6];
    float* out = (float*)d_out;

    // 1) fused prep: f-side tables (48 KB) + v-side EV table (8 MB) in one launch
    prep_fused<<<dim3(PREP1_BLOCKS + PREP2_BLOCKS), dim3(256), 0, stream>>>(
        freqs, amps, phases, ip, W, (const float4*)vp, d_ws);

    // 2) main kernel: x = bl-groups (fast, shares vocab slice), y = slices
    float4* evt4 = (float4*)((char*)d_ws + 49152);
    wave_main<<<dim3(BLTOT / BLT, NSLICE), dim3(VPB), 0, stream>>>(
        evt4, d_ws, b, out);
}

// Round 14
// 98.650 us; speedup vs baseline: 3.2292x; 3.2292x over previous
//
#include <hip/hip_runtime.h>
#include <math.h>

#define VOCAB   32000
#define BLTOT   128    // B*L
#define HTOT    64     // H = 8 heads * 8 hph
#define BLT     4      // bl rows accumulated per thread
#define VPB     256    // threads per block (4 waves)
#define VT      4      // vocab rows per thread
#define SLICE   (VPB * VT)                           // 1024 vocab rows per block
#define NSLICE  ((VOCAB + SLICE - 1) / SLICE)        // 32 (tail-guarded)

#define PREP1_BLOCKS 32                              // 8192 threads for f-side
#define PREP2_BLOCKS ((VOCAB * 2 + 255) / 256)       // 250 blocks for EV table

#define LOG2E   1.44269504088896340736f

typedef __fp16 h2 __attribute__((ext_vector_type(2)));

// ---------------------------------------------------------------------------
// Fused prep (single launch, block-range partitioned):
//  blocks [0, 32):    f-side f16 tables in ws (block-uniform in main -> s_load)
//    arrA [bl][jj][8]: {ef0..3, emf0..3} at ws+0      (32 KB)
//    arrC [bl][jj][4]: {cw0..3}          at ws+32768  (16 KB)
//  blocks [32, 282):  v-side exp table EV[jj][v] = {e^v0..3, e^-v0..3} f16,
//    8 MB at ws+49152. Thread = (v, half): reads its own 128 B contiguous
//    vp chunk, writes lane-consecutive in v (coalesced).
//  exp(-|f-v|) = min(ef*e^-v, emf*e^v); one-sided f16 overflow healed by min.
// ---------------------------------------------------------------------------
__global__ void prep_fused(const float* __restrict__ freqs,
                           const float* __restrict__ amps,
                           const float* __restrict__ phases,
                           const float* __restrict__ ip,
                           const float* __restrict__ W,
                           const float4* __restrict__ vp4,
                           void* __restrict__ ws) {
    if (blockIdx.x < PREP1_BLOCKS) {
        int t = blockIdx.x * blockDim.x + threadIdx.x;   // 0 .. 8191
        int bl = t >> 6;
        int j  = t & 63;
        float fe = freqs[t] * LOG2E;
        float cw = amps[t] * cosf(phases[t] - ip[j]) * W[j >> 3];
        int jj = j >> 2, u = j & 3;
        __fp16* pA = (__fp16*)ws;
        __fp16* pC = (__fp16*)((char*)ws + 32768);
        int ia = (bl * 16 + jj) * 8;
        pA[ia + u]     = (__fp16)__builtin_amdgcn_exp2f(fe);    // e^f
        pA[ia + 4 + u] = (__fp16)__builtin_amdgcn_exp2f(-fe);   // e^-f
        pC[(bl * 16 + jj) * 4 + u] = (__fp16)cw;
    } else {
        int t = (blockIdx.x - PREP1_BLOCKS) * blockDim.x + threadIdx.x;  // 0 .. 63999
        if (t >= VOCAB * 2) return;
        int v   = t >> 1;
        int jj0 = (t & 1) * 8;
        float4* evt4 = (float4*)((char*)ws + 49152);
#pragma unroll
        for (int l = 0; l < 8; ++l) {
            int jj = jj0 + l;
            const float4 vf = vp4[v * 16 + jj];
            float ax = vf.x * LOG2E, ay = vf.y * LOG2E;
            float az = vf.z * LOG2E, aw = vf.w * LOG2E;
            h2 ev01  = __builtin_amdgcn_cvt_pkrtz(__builtin_amdgcn_exp2f( ax),
                                                  __builtin_amdgcn_exp2f( ay));
            h2 ev23  = __builtin_amdgcn_cvt_pkrtz(__builtin_amdgcn_exp2f( az),
                                                  __builtin_amdgcn_exp2f( aw));
            h2 emv01 = __builtin_amdgcn_cvt_pkrtz(__builtin_amdgcn_exp2f(-ax),
                                                  __builtin_amdgcn_exp2f(-ay));
            h2 emv23 = __builtin_amdgcn_cvt_pkrtz(__builtin_amdgcn_exp2f(-az),
                                                  __builtin_amdgcn_exp2f(-aw));
            float4 o;
            o.x = __builtin_bit_cast(float, ev01);
            o.y = __builtin_bit_cast(float, ev23);
            o.z = __builtin_bit_cast(float, emv01);
            o.w = __builtin_bit_cast(float, emv23);
            evt4[jj * VOCAB + v] = o;                    // lane-consecutive in v
        }
    }
}

// ---------------------------------------------------------------------------
// Main (R12-exact structure: unroll 2, no SW pipeline -- R13's full unroll +
// prefetch spilled acc/EV to scratch, WRITE_SIZE 16->292 MB, 5x regression).
// Grid (x = 32 bl-groups, y = 32 vocab slices); consecutive ids share a
// vocab slice (XCD round-robin keeps it L2-resident). Thread owns VT=4
// vocab rows x BLT=4 bl rows. f-side table via block-uniform pointers ->
// s_load on the scalar pipe (no LDS, no barrier). Only R14 delta vs R12:
// fully-OOB tail threads exit immediately (no barriers -> legal).
// ---------------------------------------------------------------------------
__global__ __launch_bounds__(VPB, 8) void
wave_main(const float4* __restrict__ evt4,  // EV table [16][VOCAB]
          const void* __restrict__ uni,     // ws f16 f-side tables
          const float* __restrict__ bptr,   // bias (1 elem)
          float* __restrict__ out) {        // (B*L, VOCAB)
    const int tid = threadIdx.x;
    const int bl0 = blockIdx.x * BLT;                 // 128 = 32*4 exact
    const int v0  = blockIdx.y * SLICE + tid;

    if (v0 >= VOCAB) return;   // tail slice: all k's OOB, no barriers below

    const float4* gA = (const float4*)((const char*)uni + (size_t)bl0 * 256);
    const float2* gC = (const float2*)((const char*)uni + 32768 + (size_t)bl0 * 128);

    int vidx[VT];
#pragma unroll
    for (int k = 0; k < VT; ++k) {
        int v = v0 + k * VPB;
        vidx[k] = v < VOCAB ? v : VOCAB - 1;   // clamp loads; stores guarded
    }

    float acc[BLT][VT];
#pragma unroll
    for (int i = 0; i < BLT; ++i)
#pragma unroll
        for (int k = 0; k < VT; ++k) acc[i][k] = 0.0f;

#pragma unroll 2
    for (int jj = 0; jj < 16; ++jj) {
        h2 evA[VT], evB[VT], emvA[VT], emvB[VT];
#pragma unroll
        for (int k = 0; k < VT; ++k) {
            const float4 E = evt4[jj * VOCAB + vidx[k]];   // coalesced 16B
            evA[k]  = __builtin_bit_cast(h2, E.x);
            evB[k]  = __builtin_bit_cast(h2, E.y);
            emvA[k] = __builtin_bit_cast(h2, E.z);
            emvB[k] = __builtin_bit_cast(h2, E.w);
        }
#pragma unroll
        for (int i = 0; i < BLT; ++i) {
            const float4 A = gA[i * 16 + jj];         // s_load_dwordx4
            const float2 C = gC[i * 16 + jj];         // s_load_dwordx2
            const h2 ef01 = __builtin_bit_cast(h2, A.x);
            const h2 ef23 = __builtin_bit_cast(h2, A.y);
            const h2 em01 = __builtin_bit_cast(h2, A.z);
            const h2 em23 = __builtin_bit_cast(h2, A.w);
            const h2 cw01 = __builtin_bit_cast(h2, C.x);
            const h2 cw23 = __builtin_bit_cast(h2, C.y);
#pragma unroll
            for (int k = 0; k < VT; ++k) {
                h2 m01 = __builtin_elementwise_min(ef01 * emvA[k], em01 * evA[k]);
                h2 m23 = __builtin_elementwise_min(ef23 * emvB[k], em23 * evB[k]);
                acc[i][k] = __builtin_amdgcn_fdot2(m01, cw01, acc[i][k], false);
                acc[i][k] = __builtin_amdgcn_fdot2(m23, cw23, acc[i][k], false);
            }
        }
    }

    const float b0 = bptr[0];
#pragma unroll
    for (int i = 0; i < BLT; ++i)
#pragma unroll
        for (int k = 0; k < VT; ++k) {
            int v = v0 + k * VPB;
            if (v < VOCAB)
                out[(bl0 + i) * VOCAB + v] = acc[i][k] + b0;   // coalesced per k
        }
}

extern "C" void kernel_launch(void* const* d_in, const int* in_sizes, int n_in,
                              void* d_out, int out_size, void* d_ws, size_t ws_size,
                              hipStream_t stream) {
    const float* freqs  = (const float*)d_in[0];
    const float* amps   = (const float*)d_in[1];
    const float* phases = (const float*)d_in[2];
    const float* vp     = (const float*)d_in[3];
    const float* ip     = (const float*)d_in[4];
    const float* W      = (const float*)d_in[5];
    const float* b      = (const float*)d_in[6];
    float* out = (float*)d_out;

    // 1) fused prep: f-side tables (48 KB) + v-side EV table (8 MB) in one launch
    prep_fused<<<dim3(PREP1_BLOCKS + PREP2_BLOCKS), dim3(256), 0, stream>>>(
        freqs, amps, phases, ip, W, (const float4*)vp, d_ws);

    // 2) main kernel: x = bl-groups (fast, shares vocab slice), y = slices
    float4* evt4 = (float4*)((char*)d_ws + 49152);
    wave_main<<<dim3(BLTOT / BLT, NSLICE), dim3(VPB), 0, stream>>>(
        evt4, d_ws, b, out);
}